// Round 10
// baseline (3819.411 us; speedup 1.0000x reference)
//
#include <hip/hip_runtime.h>
#include <hip/hip_bf16.h>

// Int8Linear: out[B,T,OUT] = x[B,T,IN] @ (w_int8*scale)^T + bias
// M = B*T = 8192, N = OUT = 11008, K = IN = 4096
// Full-int8: x per-token absmax-quantized, W exact i8, mfma_i32_16x16x64_i8,
// exact i32 accum, epilogue acc*xs[m]*wscale[n]+bias.
// R10: single variable vs R9 = ring-4 -> ring-2 (LDS 128->64 KB) so TWO
// blocks co-reside per CU. Cross-block waves are not barrier-locked: one
// block's MFMA phase overlaps the other's LDS/barrier phase (m114 mechanism)
// — attacks the measured additive {read-phase}+{MFMA-phase} serialization
// that R6/R7/R8 schedule variants could not break at 1 block/CU.
#define MDIM 8192
#define NDIM 11008
#define KDIM 4096

#define BM 256
#define BN 256
#define BK 64
#define NT (KDIM / BK)   // 64 K-tiles

typedef __attribute__((ext_vector_type(4))) int int4v;

// ---------------- x quantization: per-token absmax -> i8 ----------------

__global__ __launch_bounds__(256) void quant_x_kernel(const float* __restrict__ x,
                                                      int* __restrict__ q,
                                                      float* __restrict__ xs) {
  int row = blockIdx.x;
  int tid = threadIdx.x;
  const float4* xr = (const float4*)(x + (size_t)row * KDIM);
  float4 v[4];
  float amax = 0.f;
#pragma unroll
  for (int i = 0; i < 4; ++i) {
    v[i] = xr[tid + i * 256];
    amax = fmaxf(amax, fmaxf(fmaxf(fabsf(v[i].x), fabsf(v[i].y)),
                             fmaxf(fabsf(v[i].z), fabsf(v[i].w))));
  }
#pragma unroll
  for (int off = 32; off; off >>= 1)
    amax = fmaxf(amax, __shfl_xor(amax, off));
  __shared__ float smax[4];
  if ((tid & 63) == 0) smax[tid >> 6] = amax;
  __syncthreads();
  amax = fmaxf(fmaxf(smax[0], smax[1]), fmaxf(smax[2], smax[3]));
  amax = fmaxf(amax, 1e-20f);
  float inv = 127.f / amax;
  if (tid == 0) xs[row] = amax * (1.f / 127.f);
  int* qr = q + (size_t)row * (KDIM / 4);
#pragma unroll
  for (int i = 0; i < 4; ++i) {
    int a = (int)rintf(v[i].x * inv) & 255;
    int b = (int)rintf(v[i].y * inv) & 255;
    int c = (int)rintf(v[i].z * inv) & 255;
    int d = (int)rintf(v[i].w * inv);
    qr[tid + i * 256] = a | (b << 8) | (c << 16) | (d << 24);
  }
}

// ---------------- W pack: int32 -> i8 (exact) ----------------

__global__ void cvt_w_kernel(const int* __restrict__ w, int* __restrict__ q, int n) {
  int stride = gridDim.x * blockDim.x;
  for (int i = blockIdx.x * blockDim.x + threadIdx.x; i < n; i += stride) {
    int4v v = *(const int4v*)(w + (size_t)i * 4);
    q[i] = (v.x & 255) | ((v.y & 255) << 8) | ((v.z & 255) << 16) | (v.w << 24);
  }
}

// ---------------- 256x256 int8 MFMA GEMM (ring-2, 2 blocks/CU) ------
// LDS: per operand [2][256 rows][64 B] = 32 KB; total 64 KB -> 2 blocks/CU.
// Tile T = {12 ds_read_b128 (slot T&1), stage A+B of T+1 (slot T&1^1),
//           2 MFMA half-clusters, vmcnt(0), 1 barrier}.
// WAR safe: slot (T+1)&1 last read during T-1, one barrier back; readers'
// lgkm is drained by their own MFMA use before that barrier.

#define SBARR() __builtin_amdgcn_sched_barrier(0)
#define BARR()  __builtin_amdgcn_s_barrier()
#define VMW_(n) asm volatile("s_waitcnt vmcnt(" #n ")" ::: "memory")
#define VMW(n)  VMW_(n)

#define GLL(SRC, DST) \
  __builtin_amdgcn_global_load_lds( \
      (const __attribute__((address_space(1))) void*)(SRC), \
      (__attribute__((address_space(3))) void*)(DST), 16, 0, 0)

// stage one operand's K-tile T (16KB): 2 loads/thread, linear LDS dest
#define STAGE(GSRC, LBASE, BUFI, T) do { \
    const char* _s = (GSRC) + (T) * 64; \
    GLL(_s, (LBASE) + (BUFI) * 16384 + w * 1024); \
    GLL(_s + rstep, (LBASE) + (BUFI) * 16384 + w * 1024 + 8192); \
  } while (0)

// swizzled fragment read (16B = 16 i8 along K for one row)
#define RD(LB, BUFI, ROW) \
  (*(const int4v*)((LB) + (BUFI) * 16384 + (ROW) * 64 + kbs))

#define MFMA16(AF, MOFF) do { \
    _Pragma("unroll") for (int mi = 0; mi < 4; ++mi) \
    _Pragma("unroll") for (int ni = 0; ni < 4; ++ni) \
      acc[(MOFF) + mi][ni] = __builtin_amdgcn_mfma_i32_16x16x64_i8( \
          af[mi], bf[ni], acc[(MOFF) + mi][ni], 0, 0, 0); \
  } while (0)

// One K-tile. B_ = LDS slot (compile-time 0/1), SD = stage T+1 into B_^1,
// TAIL = last tile (skip trailing wait+barrier).
#define KT(T, B_, SD, TAIL) do { \
    _Pragma("unroll") for (int ni = 0; ni < 4; ++ni) bf[ni] = RD(ldsB, B_, brow0 + ni * 16); \
    _Pragma("unroll") for (int mi = 0; mi < 4; ++mi) af[mi] = RD(ldsA, B_, arow0 + mi * 16); \
    if (SD) STAGE(gAs, ldsA, (B_) ^ 1, (T) + 1); \
    SBARR(); \
    __builtin_amdgcn_s_setprio(1); MFMA16(af, 0); __builtin_amdgcn_s_setprio(0); \
    SBARR(); \
    _Pragma("unroll") for (int mi = 0; mi < 4; ++mi) af[mi] = RD(ldsA, B_, arow0 + 64 + mi * 16); \
    if (SD) STAGE(gBs, ldsB, (B_) ^ 1, (T) + 1); \
    SBARR(); \
    __builtin_amdgcn_s_setprio(1); MFMA16(af, 4); __builtin_amdgcn_s_setprio(0); \
    SBARR(); \
    if (!(TAIL)) { VMW(0); BARR(); SBARR(); } \
  } while (0)

__global__ __launch_bounds__(512, 4) void gemm_i8_kernel(
    const char* __restrict__ A,
    const char* __restrict__ Bt,
    const float* __restrict__ xs,
    const float* __restrict__ scale,
    const float* __restrict__ bias,
    float* __restrict__ C)
{
  __shared__ __attribute__((aligned(16))) char As[2][256][64];  // 32 KB
  __shared__ __attribute__((aligned(16))) char Bs[2][256][64];  // 32 KB

  // grid = 32*43 = 1376 = 8*172
  int bid = blockIdx.x;
  int cpx = gridDim.x >> 3;                 // 172
  int swz = (bid & 7) * cpx + (bid >> 3);   // bijective XCD swizzle
  // 8x4 supertile order (bijective; ragged last col 8x3): 32 co-scheduled
  // blocks share 8 A + 4 B panels (12 MB).
  int srow = swz / 344;
  int rem  = swz - srow * 344;
  int scol, q;
  if (rem < 320) { scol = rem >> 5; q = rem & 31; }
  else           { scol = 10;       q = rem - 320; }
  int brow = (srow * 8 + (q & 7)) * BM;
  int bcol = (scol * 4 + (q >> 3)) * BN;

  int tid  = threadIdx.x;
  int lane = tid & 63;
  int w    = tid >> 6;
  int wr   = (w >> 2) & 1;   // M-wave (2)
  int wc   = w & 3;          // N-wave (4)

  int ra = lane & 15;                         // fragment row within 16
  int kb = (lane >> 4) * 16;                  // byte offset along K (64B row)
  int kbs = kb ^ (((ra >> 1) & 3) << 4);      // proven 0-conflict swizzle

  int arow0 = wr * 128 + ra;                  // wave's A base row + frag row
  int brow0 = wc * 64 + ra;                   // wave's B base row + frag row

  // staging: thread granule g = w*64+lane -> (row srw, dst granule lane&3);
  // inverse-swizzled source k-granule (lane-constant)
  int srw = w * 16 + (lane >> 2);
  int csrc = (lane & 3) ^ ((lane >> 3) & 3);
  const char* gAs = A  + (size_t)(brow + srw) * KDIM + csrc * 16;
  const char* gBs = Bt + (size_t)(bcol + srw) * KDIM + csrc * 16;
  const size_t rstep = (size_t)128 * KDIM;

  char* ldsA = &As[0][0][0];
  char* ldsB = &Bs[0][0][0];

  int4v acc[8][4] = {};
  int4v af[4], bf[4];

  // prologue: tile 0 into slot 0; drain
  STAGE(gAs, ldsA, 0, 0);  STAGE(gBs, ldsB, 0, 0);
  VMW(0); BARR(); SBARR();

  // steady: tiles 0..61 (stage T+1 into opposite slot, vmcnt(0) + barrier)
  for (int t = 0; t < 62; t += 2) {
    KT(t,     0, 1, 0);
    KT(t + 1, 1, 1, 0);
  }
  KT(62, 0, 1, 0);   // stages 63 into slot 1
  KT(63, 1, 0, 1);   // last tile: no stage, no trailing wait

  // epilogue: C/D layout col = lane&15, row = (lane>>4)*4 + reg (dtype-indep)
  // non-temporal stores: write stream must not churn L2/L3
  int col0 = bcol + wc * 64 + ra;
  int row0 = brow + wr * 128 + (lane >> 4) * 4;
  float xr_[8][4];
#pragma unroll
  for (int m = 0; m < 8; ++m)
#pragma unroll
    for (int j = 0; j < 4; ++j)
      xr_[m][j] = xs[row0 + m * 16 + j];
#pragma unroll
  for (int n = 0; n < 4; ++n) {
    int ng = col0 + n * 16;
    float sc = scale[ng];
    float bi = bias[ng];
#pragma unroll
    for (int m = 0; m < 8; ++m) {
      int rg = row0 + m * 16;
#pragma unroll
      for (int j = 0; j < 4; ++j)
        __builtin_nontemporal_store((float)acc[m][n][j] * (xr_[m][j] * sc) + bi,
                                    &C[(size_t)(rg + j) * NDIM + ng]);
    }
  }
}

// ---------------- fallback (only if d_ws is too small) ----------------

__global__ void naive_kernel(const float* __restrict__ x, const int* __restrict__ w,
                             const float* __restrict__ scale, const float* __restrict__ bias,
                             float* __restrict__ out)
{
  int n = blockIdx.x * blockDim.x + threadIdx.x;
  int m = blockIdx.y;
  if (n >= NDIM) return;
  const float* xr = x + (size_t)m * KDIM;
  const int* wrow = w + (size_t)n * KDIM;
  float s = 0.f;
  for (int k = 0; k < KDIM; ++k) s += xr[k] * (float)wrow[k];
  out[(size_t)m * NDIM + n] = s * scale[n] + bias[n];
}

// ---------------- launcher ----------------

extern "C" void kernel_launch(void* const* d_in, const int* in_sizes, int n_in,
                              void* d_out, int out_size, void* d_ws, size_t ws_size,
                              hipStream_t stream) {
  const float* x      = (const float*)d_in[0];
  const int*   w8     = (const int*)d_in[1];
  const float* wscale = (const float*)d_in[2];
  const float* bias   = (const float*)d_in[3];
  float* out = (float*)d_out;

  size_t aq = (size_t)MDIM * KDIM;   // 33.5 MB i8
  size_t bq = (size_t)NDIM * KDIM;   // 45.1 MB i8
  size_t xb = (size_t)MDIM * 4;      // 32 KB scales

  if (ws_size >= aq + bq + xb) {
    char* Aq = (char*)d_ws;
    char* Bq = (char*)d_ws + aq;
    float* xsp = (float*)((char*)d_ws + aq + bq);
    quant_x_kernel<<<MDIM, 256, 0, stream>>>(x, (int*)Aq, xsp);
    cvt_w_kernel<<<2048, 256, 0, stream>>>(w8, (int*)Bq, NDIM * KDIM / 4);
    gemm_i8_kernel<<<(MDIM / BM) * (NDIM / BN), 512, 0, stream>>>(
        Aq, Bq, xsp, wscale, bias, out);
  } else {
    naive_kernel<<<dim3((NDIM + 255) / 256, MDIM), 256, 0, stream>>>(x, w8, wscale, bias, out);
  }
}

// Round 11
// 490.414 us; speedup vs baseline: 7.7881x; 7.7881x over previous
//
#include <hip/hip_runtime.h>
#include <hip/hip_bf16.h>

// Int8Linear: out[B,T,OUT] = x[B,T,IN] @ (w_int8*scale)^T + bias
// M = B*T = 8192, N = OUT = 11008, K = IN = 4096
// Full-int8: x per-token absmax-quantized, W exact i8, mfma_i32_16x16x64_i8,
// exact i32 accum, epilogue acc*xs[m]*wscale[n]+bias.
// R11: R10 retried with CORRECT launch bounds. R10's (512,4) made the
// compiler allocate 64 VGPR -> ~70 regs spilled to scratch (11.4 GB write
// traffic, 10x slowdown). (512,2) gives a 128-VGPR budget; body needs ~112
// -> no spills, and 112<=128 + 64KB LDS => 2 blocks/CU for real. This runs
// the cross-block overlap experiment (one block's MFMA covers the other's
// ds_read/vmcnt/barrier phase) that R10 was supposed to be.
#define MDIM 8192
#define NDIM 11008
#define KDIM 4096

#define BM 256
#define BN 256
#define BK 64
#define NT (KDIM / BK)   // 64 K-tiles

typedef __attribute__((ext_vector_type(4))) int int4v;

// ---------------- x quantization: per-token absmax -> i8 ----------------

__global__ __launch_bounds__(256) void quant_x_kernel(const float* __restrict__ x,
                                                      int* __restrict__ q,
                                                      float* __restrict__ xs) {
  int row = blockIdx.x;
  int tid = threadIdx.x;
  const float4* xr = (const float4*)(x + (size_t)row * KDIM);
  float4 v[4];
  float amax = 0.f;
#pragma unroll
  for (int i = 0; i < 4; ++i) {
    v[i] = xr[tid + i * 256];
    amax = fmaxf(amax, fmaxf(fmaxf(fabsf(v[i].x), fabsf(v[i].y)),
                             fmaxf(fabsf(v[i].z), fabsf(v[i].w))));
  }
#pragma unroll
  for (int off = 32; off; off >>= 1)
    amax = fmaxf(amax, __shfl_xor(amax, off));
  __shared__ float smax[4];
  if ((tid & 63) == 0) smax[tid >> 6] = amax;
  __syncthreads();
  amax = fmaxf(fmaxf(smax[0], smax[1]), fmaxf(smax[2], smax[3]));
  amax = fmaxf(amax, 1e-20f);
  float inv = 127.f / amax;
  if (tid == 0) xs[row] = amax * (1.f / 127.f);
  int* qr = q + (size_t)row * (KDIM / 4);
#pragma unroll
  for (int i = 0; i < 4; ++i) {
    int a = (int)rintf(v[i].x * inv) & 255;
    int b = (int)rintf(v[i].y * inv) & 255;
    int c = (int)rintf(v[i].z * inv) & 255;
    int d = (int)rintf(v[i].w * inv);
    qr[tid + i * 256] = a | (b << 8) | (c << 16) | (d << 24);
  }
}

// ---------------- W pack: int32 -> i8 (exact) ----------------

__global__ void cvt_w_kernel(const int* __restrict__ w, int* __restrict__ q, int n) {
  int stride = gridDim.x * blockDim.x;
  for (int i = blockIdx.x * blockDim.x + threadIdx.x; i < n; i += stride) {
    int4v v = *(const int4v*)(w + (size_t)i * 4);
    q[i] = (v.x & 255) | ((v.y & 255) << 8) | ((v.z & 255) << 16) | (v.w << 24);
  }
}

// ---------------- 256x256 int8 MFMA GEMM (ring-2, 2 blocks/CU) ------
// LDS: per operand [2][256 rows][64 B] = 32 KB; total 64 KB -> 2 blocks/CU.
// Tile T = {12 ds_read_b128 (slot T&1), stage A+B of T+1 (slot T&1^1),
//           2 MFMA half-clusters, vmcnt(0), 1 barrier}.
// WAR safe: slot (T+1)&1 last read during T-1, one barrier back.

#define SBARR() __builtin_amdgcn_sched_barrier(0)
#define BARR()  __builtin_amdgcn_s_barrier()
#define VMW_(n) asm volatile("s_waitcnt vmcnt(" #n ")" ::: "memory")
#define VMW(n)  VMW_(n)

#define GLL(SRC, DST) \
  __builtin_amdgcn_global_load_lds( \
      (const __attribute__((address_space(1))) void*)(SRC), \
      (__attribute__((address_space(3))) void*)(DST), 16, 0, 0)

// stage one operand's K-tile T (16KB): 2 loads/thread, linear LDS dest
#define STAGE(GSRC, LBASE, BUFI, T) do { \
    const char* _s = (GSRC) + (T) * 64; \
    GLL(_s, (LBASE) + (BUFI) * 16384 + w * 1024); \
    GLL(_s + rstep, (LBASE) + (BUFI) * 16384 + w * 1024 + 8192); \
  } while (0)

// swizzled fragment read (16B = 16 i8 along K for one row)
#define RD(LB, BUFI, ROW) \
  (*(const int4v*)((LB) + (BUFI) * 16384 + (ROW) * 64 + kbs))

#define MFMA16(AF, MOFF) do { \
    _Pragma("unroll") for (int mi = 0; mi < 4; ++mi) \
    _Pragma("unroll") for (int ni = 0; ni < 4; ++ni) \
      acc[(MOFF) + mi][ni] = __builtin_amdgcn_mfma_i32_16x16x64_i8( \
          af[mi], bf[ni], acc[(MOFF) + mi][ni], 0, 0, 0); \
  } while (0)

// One K-tile. B_ = LDS slot (compile-time 0/1), SD = stage T+1 into B_^1,
// TAIL = last tile (skip trailing wait+barrier).
#define KT(T, B_, SD, TAIL) do { \
    _Pragma("unroll") for (int ni = 0; ni < 4; ++ni) bf[ni] = RD(ldsB, B_, brow0 + ni * 16); \
    _Pragma("unroll") for (int mi = 0; mi < 4; ++mi) af[mi] = RD(ldsA, B_, arow0 + mi * 16); \
    if (SD) STAGE(gAs, ldsA, (B_) ^ 1, (T) + 1); \
    SBARR(); \
    __builtin_amdgcn_s_setprio(1); MFMA16(af, 0); __builtin_amdgcn_s_setprio(0); \
    SBARR(); \
    _Pragma("unroll") for (int mi = 0; mi < 4; ++mi) af[mi] = RD(ldsA, B_, arow0 + 64 + mi * 16); \
    if (SD) STAGE(gBs, ldsB, (B_) ^ 1, (T) + 1); \
    SBARR(); \
    __builtin_amdgcn_s_setprio(1); MFMA16(af, 4); __builtin_amdgcn_s_setprio(0); \
    SBARR(); \
    if (!(TAIL)) { VMW(0); BARR(); SBARR(); } \
  } while (0)

__global__ __launch_bounds__(512, 2) void gemm_i8_kernel(
    const char* __restrict__ A,
    const char* __restrict__ Bt,
    const float* __restrict__ xs,
    const float* __restrict__ scale,
    const float* __restrict__ bias,
    float* __restrict__ C)
{
  __shared__ __attribute__((aligned(16))) char As[2][256][64];  // 32 KB
  __shared__ __attribute__((aligned(16))) char Bs[2][256][64];  // 32 KB

  // grid = 32*43 = 1376 = 8*172
  int bid = blockIdx.x;
  int cpx = gridDim.x >> 3;                 // 172
  int swz = (bid & 7) * cpx + (bid >> 3);   // bijective XCD swizzle
  // 8x4 supertile order (bijective; ragged last col 8x3): co-scheduled
  // blocks share 8 A + 4 B panels (12 MB).
  int srow = swz / 344;
  int rem  = swz - srow * 344;
  int scol, q;
  if (rem < 320) { scol = rem >> 5; q = rem & 31; }
  else           { scol = 10;       q = rem - 320; }
  int brow = (srow * 8 + (q & 7)) * BM;
  int bcol = (scol * 4 + (q >> 3)) * BN;

  int tid  = threadIdx.x;
  int lane = tid & 63;
  int w    = tid >> 6;
  int wr   = (w >> 2) & 1;   // M-wave (2)
  int wc   = w & 3;          // N-wave (4)

  int ra = lane & 15;                         // fragment row within 16
  int kb = (lane >> 4) * 16;                  // byte offset along K (64B row)
  int kbs = kb ^ (((ra >> 1) & 3) << 4);      // proven 0-conflict swizzle

  int arow0 = wr * 128 + ra;                  // wave's A base row + frag row
  int brow0 = wc * 64 + ra;                   // wave's B base row + frag row

  // staging: thread granule g = w*64+lane -> (row srw, dst granule lane&3);
  // inverse-swizzled source k-granule (lane-constant)
  int srw = w * 16 + (lane >> 2);
  int csrc = (lane & 3) ^ ((lane >> 3) & 3);
  const char* gAs = A  + (size_t)(brow + srw) * KDIM + csrc * 16;
  const char* gBs = Bt + (size_t)(bcol + srw) * KDIM + csrc * 16;
  const size_t rstep = (size_t)128 * KDIM;

  char* ldsA = &As[0][0][0];
  char* ldsB = &Bs[0][0][0];

  int4v acc[8][4] = {};
  int4v af[4], bf[4];

  // prologue: tile 0 into slot 0; drain
  STAGE(gAs, ldsA, 0, 0);  STAGE(gBs, ldsB, 0, 0);
  VMW(0); BARR(); SBARR();

  // steady: tiles 0..61 (stage T+1 into opposite slot, vmcnt(0) + barrier)
  for (int t = 0; t < 62; t += 2) {
    KT(t,     0, 1, 0);
    KT(t + 1, 1, 1, 0);
  }
  KT(62, 0, 1, 0);   // stages 63 into slot 1
  KT(63, 1, 0, 1);   // last tile: no stage, no trailing wait

  // epilogue: C/D layout col = lane&15, row = (lane>>4)*4 + reg (dtype-indep)
  // non-temporal stores: write stream must not churn L2/L3
  int col0 = bcol + wc * 64 + ra;
  int row0 = brow + wr * 128 + (lane >> 4) * 4;
  float xr_[8][4];
#pragma unroll
  for (int m = 0; m < 8; ++m)
#pragma unroll
    for (int j = 0; j < 4; ++j)
      xr_[m][j] = xs[row0 + m * 16 + j];
#pragma unroll
  for (int n = 0; n < 4; ++n) {
    int ng = col0 + n * 16;
    float sc = scale[ng];
    float bi = bias[ng];
#pragma unroll
    for (int m = 0; m < 8; ++m) {
      int rg = row0 + m * 16;
#pragma unroll
      for (int j = 0; j < 4; ++j)
        __builtin_nontemporal_store((float)acc[m][n][j] * (xr_[m][j] * sc) + bi,
                                    &C[(size_t)(rg + j) * NDIM + ng]);
    }
  }
}

// ---------------- fallback (only if d_ws is too small) ----------------

__global__ void naive_kernel(const float* __restrict__ x, const int* __restrict__ w,
                             const float* __restrict__ scale, const float* __restrict__ bias,
                             float* __restrict__ out)
{
  int n = blockIdx.x * blockDim.x + threadIdx.x;
  int m = blockIdx.y;
  if (n >= NDIM) return;
  const float* xr = x + (size_t)m * KDIM;
  const int* wrow = w + (size_t)n * KDIM;
  float s = 0.f;
  for (int k = 0; k < KDIM; ++k) s += xr[k] * (float)wrow[k];
  out[(size_t)m * NDIM + n] = s * scale[n] + bias[n];
}

// ---------------- launcher ----------------

extern "C" void kernel_launch(void* const* d_in, const int* in_sizes, int n_in,
                              void* d_out, int out_size, void* d_ws, size_t ws_size,
                              hipStream_t stream) {
  const float* x      = (const float*)d_in[0];
  const int*   w8     = (const int*)d_in[1];
  const float* wscale = (const float*)d_in[2];
  const float* bias   = (const float*)d_in[3];
  float* out = (float*)d_out;

  size_t aq = (size_t)MDIM * KDIM;   // 33.5 MB i8
  size_t bq = (size_t)NDIM * KDIM;   // 45.1 MB i8
  size_t xb = (size_t)MDIM * 4;      // 32 KB scales

  if (ws_size >= aq + bq + xb) {
    char* Aq = (char*)d_ws;
    char* Bq = (char*)d_ws + aq;
    float* xsp = (float*)((char*)d_ws + aq + bq);
    quant_x_kernel<<<MDIM, 256, 0, stream>>>(x, (int*)Aq, xsp);
    cvt_w_kernel<<<2048, 256, 0, stream>>>(w8, (int*)Bq, NDIM * KDIM / 4);
    gemm_i8_kernel<<<(MDIM / BM) * (NDIM / BN), 512, 0, stream>>>(
        Aq, Bq, xsp, wscale, bias, out);
  } else {
    naive_kernel<<<dim3((NDIM + 255) / 256, MDIM), 256, 0, stream>>>(x, w8, wscale, bias, out);
  }
}